// Round 4
// baseline (2173.389 us; speedup 1.0000x reference)
//
#include <hip/hip_runtime.h>
#include <hip/hip_bf16.h>
#include <stdint.h>

#define TOK  4096
#define DIM  2048
#define HID  4096
#define ODIM 2048
#define NEXP 8
#define KSEL 5

typedef __bf16 bf16x8 __attribute__((ext_vector_type(8)));
typedef float  f32x4  __attribute__((ext_vector_type(4)));
typedef unsigned short ushort8 __attribute__((ext_vector_type(8)));

__device__ __forceinline__ uint16_t f2bf(float f) {
  uint32_t u = __float_as_uint(f);
  u += 0x7FFFu + ((u >> 16) & 1u);   // round-to-nearest-even
  return (uint16_t)(u >> 16);
}
__device__ __forceinline__ float bf2f(uint16_t h) {
  uint32_t u = ((uint32_t)h) << 16;
  return __uint_as_float(u);
}

#define GLD16(g, l) __builtin_amdgcn_global_load_lds(                      \
    (const __attribute__((address_space(1))) void*)(g),                    \
    (__attribute__((address_space(3))) void*)(l), 16, 0, 0)

// ---------------- convert kernels ----------------

__global__ void cast_x_kernel(const float* __restrict__ in,
                              uint16_t* __restrict__ out, int n4) {
  int i = blockIdx.x * blockDim.x + threadIdx.x;
  if (i >= n4) return;
  float4 v = ((const float4*)in)[i];
  ushort4 o;
  o.x = f2bf(v.x); o.y = f2bf(v.y); o.z = f2bf(v.z); o.w = f2bf(v.w);
  ((ushort4*)out)[i] = o;
}

// out[c*R + r] = bf16(in[r*C + c]), batched over blockIdx.z
__global__ void transpose_cast_kernel(const float* __restrict__ in,
                                      uint16_t* __restrict__ out,
                                      int R, int C, long inBatch, long outBatch) {
  __shared__ float tile[32][33];
  const float* src = in + (size_t)blockIdx.z * inBatch;
  uint16_t*    dst = out + (size_t)blockIdx.z * outBatch;
  int c0 = blockIdx.x * 32, r0 = blockIdx.y * 32;
  int tx = threadIdx.x, ty = threadIdx.y;   // (32, 8)
#pragma unroll
  for (int i = 0; i < 4; ++i)
    tile[ty + i * 8][tx] = src[(size_t)(r0 + ty + i * 8) * C + c0 + tx];
  __syncthreads();
#pragma unroll
  for (int i = 0; i < 4; ++i)
    dst[(size_t)(c0 + ty + i * 8) * R + r0 + tx] = f2bf(tile[tx][ty + i * 8]);
}

// ---------------- routing: weights + selection bitmask (pure, no atomics) ----------------

__global__ void routing_kernel(const float* __restrict__ x,
                               const float* __restrict__ Wg, const float* __restrict__ bg,
                               const float* __restrict__ Wa, const float* __restrict__ ba,
                               const float* __restrict__ Wb, const float* __restrict__ bb,
                               const float* __restrict__ sigs,
                               float* __restrict__ wts, int* __restrict__ selmask_g) {
  const int n    = blockIdx.x;
  const int lane = threadIdx.x;   // 64
  const float* xr = x + (size_t)n * DIM;

  float ga[NEXP]; float aa[32];
#pragma unroll
  for (int e = 0; e < NEXP; ++e) ga[e] = 0.f;
#pragma unroll
  for (int j = 0; j < 32; ++j) aa[j] = 0.f;

  for (int it = 0; it < DIM / 64; ++it) {
    int d = it * 64 + lane;
    float xv = xr[d];
    const float* wgr = Wg + (size_t)d * NEXP;
#pragma unroll
    for (int e = 0; e < NEXP; ++e) ga[e] += xv * wgr[e];
    const float* war = Wa + (size_t)d * 32;
#pragma unroll
    for (int j = 0; j < 32; ++j) aa[j] += xv * war[j];
  }
#pragma unroll
  for (int s = 1; s < 64; s <<= 1) {
#pragma unroll
    for (int e = 0; e < NEXP; ++e) ga[e] += __shfl_xor(ga[e], s);
#pragma unroll
    for (int j = 0; j < 32; ++j) aa[j] += __shfl_xor(aa[j], s);
  }

  float ph[16];
#pragma unroll
  for (int i = 0; i < 16; ++i) ph[i] = bb[i];
#pragma unroll
  for (int j = 0; j < 32; ++j) {
    float a = aa[j] + ba[j];
    a = a > 0.f ? a : 0.f;
#pragma unroll
    for (int i = 0; i < 16; ++i) ph[i] += a * Wb[j * 16 + i];
  }
  float nrm = 0.f;
#pragma unroll
  for (int i = 0; i < 16; ++i) nrm += ph[i] * ph[i];
  nrm = fmaxf(sqrtf(nrm), 1e-12f);

  const float invT = 0.36787944117144233f;  // 1/e
  float lg[NEXP], mx = -1e30f;
#pragma unroll
  for (int e = 0; e < NEXP; ++e) { lg[e] = (ga[e] + bg[e]) * invT; mx = fmaxf(mx, lg[e]); }
  float psum = 0.f, pr[NEXP];
#pragma unroll
  for (int e = 0; e < NEXP; ++e) { pr[e] = expf(lg[e] - mx); psum += pr[e]; }

  float eff[NEXP];
#pragma unroll
  for (int e = 0; e < NEXP; ++e) {
    const float* sg = sigs + e * 16;
    float dot = 0.f, sn = 0.f;
#pragma unroll
    for (int i = 0; i < 16; ++i) { dot += ph[i] * sg[i]; sn += sg[i] * sg[i]; }
    sn = fmaxf(sqrtf(sn), 1e-12f);
    float match = (dot / (nrm * sn) + 1.f) * 0.5f;
    eff[e] = (pr[e] / psum) * match;
  }

  int selmask = 0;
#pragma unroll
  for (int t = 0; t < KSEL; ++t) {
    int bi = 0; float bv = -1e30f;
#pragma unroll
    for (int e = 0; e < NEXP; ++e) {
      bool ok = !((selmask >> e) & 1);
      if (ok && eff[e] > bv) { bv = eff[e]; bi = e; }
    }
    selmask |= (1 << bi);
  }
  float wsum = 0.f, wv[NEXP];
#pragma unroll
  for (int e = 0; e < NEXP; ++e) {
    wv[e] = ((selmask >> e) & 1) ? eff[e] : 0.f;
    wsum += wv[e];
  }
  float inv = 1.f / (wsum + 1e-8f);
  if (lane == 0) {
#pragma unroll
    for (int e = 0; e < NEXP; ++e) wts[n * NEXP + e] = wv[e] * inv;
    selmask_g[n] = selmask;
  }
}

// ---------------- deterministic sorted list build (1 block per expert) ----------------

__global__ void listbuild_kernel(const int* __restrict__ selmask_g,
                                 const float* __restrict__ wts,
                                 int* __restrict__ cnt, int* __restrict__ base,
                                 int* __restrict__ list, int* __restrict__ slot_map,
                                 float* __restrict__ wrow) {
  const int e = blockIdx.x;      // 0..7
  const int t = threadIdx.x;     // 0..255, each owns 16 consecutive tokens
  __shared__ int cntT[256][NEXP];
  __shared__ int totAll[NEXP];
  __shared__ int sc[256];

  int msk[16];
  int c8[NEXP];
#pragma unroll
  for (int f = 0; f < NEXP; ++f) c8[f] = 0;
#pragma unroll
  for (int i = 0; i < 16; ++i) {
    msk[i] = selmask_g[t * 16 + i];
#pragma unroll
    for (int f = 0; f < NEXP; ++f) c8[f] += (msk[i] >> f) & 1;
  }
#pragma unroll
  for (int f = 0; f < NEXP; ++f) cntT[t][f] = c8[f];
  __syncthreads();

  if (t < NEXP) {
    int s = 0;
    for (int j = 0; j < 256; ++j) s += cntT[j][t];
    totAll[t] = s;
  }
  __syncthreads();

  if (e == 0 && t == 0) {
    int r = 0;
    for (int f = 0; f < NEXP; ++f) { cnt[f] = totAll[f]; base[f] = r; r += totAll[f]; }
  }
  int gbase = 0;
  for (int f = 0; f < e; ++f) gbase += totAll[f];

  // exclusive prefix over threads for expert e
  sc[t] = c8[e];
  __syncthreads();
  for (int off = 1; off < 256; off <<= 1) {
    int v = (t >= off) ? sc[t - off] : 0;
    __syncthreads();
    sc[t] += v;
    __syncthreads();
  }
  int p = sc[t] - c8[e];

#pragma unroll
  for (int i = 0; i < 16; ++i) {
    const int n = t * 16 + i;
    const int m = msk[i];
    if ((m >> e) & 1) {
      list[e * TOK + p] = n;
      const int rank = __popc(m & ((1 << e) - 1));
      slot_map[n * KSEL + rank] = gbase + p;
      wrow[gbase + p] = wts[n * NEXP + e];
      ++p;
    }
  }
}

// ---------------- GEMM1: per expert, sorted gathered rows ----------------
// grid: 1-D 8192.  d&7 = expert (== XCD via HW round-robin);  q = d>>3 is the
// XCD-local stream: groups of 8 M-tiles (4MB A resident in L2), N swept inside,
// 8 consecutive blocks share each B-panel (temporal co-location).
// hbuf[base[e]+p, col] = bf16( wrow * relu( x[list[p],:] @ W1[e][:,col] + b1[e,col] ) )

__global__ void gemm1_kernel(const uint16_t* __restrict__ xbf,
                             const uint16_t* __restrict__ W1T,
                             const int* __restrict__ cnt,
                             const int* __restrict__ base,
                             const int* __restrict__ list,
                             const float* __restrict__ wrow,
                             const float* __restrict__ b1,
                             uint16_t* __restrict__ hbuf) {
  __shared__ __attribute__((aligned(16))) uint16_t smA[128 * 64];
  __shared__ __attribute__((aligned(16))) uint16_t smB[128 * 64];
  const int d = blockIdx.x;
  const int e = d & 7;
  const int q = d >> 3;              // 0..1023
  const int grp = q >> 8;            // 4 groups of 8 M-tiles
  const int rem = q & 255;
  const int nt  = rem >> 3;          // 0..31  (N swept inside group)
  const int mt  = (grp << 3) | (rem & 7);

  const int ce = cnt[e];
  const int tileM = mt * 128;
  if (tileM >= ce) return;
  const int be    = base[e];
  const int tileN = nt * 128;
  const int tid = threadIdx.x, lane = tid & 63, wid = tid >> 6;
  const int wr = wid >> 1, wc = wid & 1;
  const int* liste = list + e * TOK;

  const uint16_t* srcA[4]; const uint16_t* srcB[4]; uint32_t lof[4];
#pragma unroll
  for (int j = 0; j < 4; ++j) {
    const int f   = (wid * 4 + j) * 64 + lane;
    const int row = f >> 3;
    const int s8  = (f & 7) ^ (row & 7);
    int p = tileM + row; p = p < ce ? p : ce - 1;
    srcA[j] = xbf + (size_t)liste[p] * DIM + s8 * 8;
    srcB[j] = W1T + ((size_t)e * HID + tileN + row) * DIM + s8 * 8;
    lof[j]  = (wid * 4 + j) * 1024;
  }

  f32x4 acc[4][4];
#pragma unroll
  for (int m = 0; m < 4; ++m)
#pragma unroll
    for (int n = 0; n < 4; ++n) acc[m][n] = (f32x4){0.f, 0.f, 0.f, 0.f};

  for (int k0 = 0; k0 < DIM; k0 += 64) {
#pragma unroll
    for (int j = 0; j < 4; ++j) {
      GLD16(srcA[j] + k0, (char*)smA + lof[j]);
      GLD16(srcB[j] + k0, (char*)smB + lof[j]);
    }
    __syncthreads();
#pragma unroll
    for (int kk = 0; kk < 2; ++kk) {
      bf16x8 av[4], bv[4];
#pragma unroll
      for (int m = 0; m < 4; ++m) {
        const int row = wr * 64 + m * 16 + (lane & 15);
        const int g   = (kk * 4 + (lane >> 4)) ^ (row & 7);
        av[m] = *(const bf16x8*)(smA + row * 64 + g * 8);
      }
#pragma unroll
      for (int n = 0; n < 4; ++n) {
        const int row = wc * 64 + n * 16 + (lane & 15);
        const int g   = (kk * 4 + (lane >> 4)) ^ (row & 7);
        bv[n] = *(const bf16x8*)(smB + row * 64 + g * 8);
      }
#pragma unroll
      for (int m = 0; m < 4; ++m)
#pragma unroll
        for (int n = 0; n < 4; ++n)
          acc[m][n] = __builtin_amdgcn_mfma_f32_16x16x32_bf16(av[m], bv[n], acc[m][n], 0, 0, 0);
    }
    __syncthreads();
  }

  const float* b1e = b1 + (size_t)e * HID;
#pragma unroll
  for (int m = 0; m < 4; ++m)
#pragma unroll
    for (int r = 0; r < 4; ++r) {
      const int p = tileM + wr * 64 + m * 16 + ((lane >> 4) << 2) + r;
      if (p < ce) {
        const float w = wrow[be + p];
        uint16_t* orow = hbuf + (size_t)(be + p) * HID;
#pragma unroll
        for (int nf = 0; nf < 4; ++nf) {
          const int col = tileN + wc * 64 + nf * 16 + (lane & 15);
          float v = acc[m][nf][r] + b1e[col];
          v = v > 0.f ? v : 0.f;
          orow[col] = f2bf(v * w);
        }
      }
    }
}

// ---------------- GEMM2: per expert, compact in / compact out (no atomics) ----------------
// grid: 1-D 4096.  d&7 = expert (== XCD); groups of 4 N-tiles (4MB B resident),
// M swept inside, 4 consecutive blocks share each A-panel.
// W2T is per-expert [E][ODIM][HID].
// obuf[base[e]+p, col] = bf16( hbuf[base[e]+p, :] @ W2[e][:, col] )

__global__ void gemm2_kernel(const uint16_t* __restrict__ hbuf,
                             const uint16_t* __restrict__ W2T,
                             const int* __restrict__ cnt,
                             const int* __restrict__ base,
                             uint16_t* __restrict__ obuf) {
  __shared__ __attribute__((aligned(16))) uint16_t smA[128 * 64];
  __shared__ __attribute__((aligned(16))) uint16_t smB[128 * 64];
  const int d = blockIdx.x;
  const int e = d & 7;
  const int q = d >> 3;              // 0..511
  const int grp = q >> 7;            // 4 groups of 4 N-tiles
  const int rem = q & 127;
  const int mt  = rem >> 2;          // 0..31 (M swept inside group)
  const int nt  = (grp << 2) | (rem & 3);

  const int ce = cnt[e];
  const int tileM = mt * 128;
  if (tileM >= ce) return;
  const int be    = base[e];
  const int tileN = nt * 128;
  const int tid = threadIdx.x, lane = tid & 63, wid = tid >> 6;
  const int wr = wid >> 1, wc = wid & 1;

  const uint16_t* srcA[4]; const uint16_t* srcB[4]; uint32_t lof[4];
#pragma unroll
  for (int j = 0; j < 4; ++j) {
    const int f   = (wid * 4 + j) * 64 + lane;
    const int row = f >> 3;
    const int s8  = (f & 7) ^ (row & 7);
    srcA[j] = hbuf + (size_t)(be + tileM + row) * HID + s8 * 8;
    srcB[j] = W2T + ((size_t)e * ODIM + tileN + row) * HID + s8 * 8;
    lof[j]  = (wid * 4 + j) * 1024;
  }

  f32x4 acc[4][4];
#pragma unroll
  for (int m = 0; m < 4; ++m)
#pragma unroll
    for (int n = 0; n < 4; ++n) acc[m][n] = (f32x4){0.f, 0.f, 0.f, 0.f};

  for (int k0 = 0; k0 < HID; k0 += 64) {
#pragma unroll
    for (int j = 0; j < 4; ++j) {
      GLD16(srcA[j] + k0, (char*)smA + lof[j]);
      GLD16(srcB[j] + k0, (char*)smB + lof[j]);
    }
    __syncthreads();
#pragma unroll
    for (int kk = 0; kk < 2; ++kk) {
      bf16x8 av[4], bv[4];
#pragma unroll
      for (int m = 0; m < 4; ++m) {
        const int row = wr * 64 + m * 16 + (lane & 15);
        const int g   = (kk * 4 + (lane >> 4)) ^ (row & 7);
        av[m] = *(const bf16x8*)(smA + row * 64 + g * 8);
      }
#pragma unroll
      for (int n = 0; n < 4; ++n) {
        const int row = wc * 64 + n * 16 + (lane & 15);
        const int g   = (kk * 4 + (lane >> 4)) ^ (row & 7);
        bv[n] = *(const bf16x8*)(smB + row * 64 + g * 8);
      }
#pragma unroll
      for (int m = 0; m < 4; ++m)
#pragma unroll
        for (int n = 0; n < 4; ++n)
          acc[m][n] = __builtin_amdgcn_mfma_f32_16x16x32_bf16(av[m], bv[n], acc[m][n], 0, 0, 0);
    }
    __syncthreads();
  }

#pragma unroll
  for (int m = 0; m < 4; ++m)
#pragma unroll
    for (int r = 0; r < 4; ++r) {
      const int p = tileM + wr * 64 + m * 16 + ((lane >> 4) << 2) + r;
      if (p < ce) {
        uint16_t* orow = obuf + (size_t)(be + p) * ODIM;
#pragma unroll
        for (int nf = 0; nf < 4; ++nf) {
          const int col = tileN + wc * 64 + nf * 16 + (lane & 15);
          orow[col] = f2bf(acc[m][nf][r]);
        }
      }
    }
}

// ---------------- reduce: out[n,:] = sum_e w*b2[e,:] + sum_{k<5} obuf[slot_k,:] ----------------

__global__ void reduce_kernel(const uint16_t* __restrict__ obuf,
                              const int* __restrict__ slot_map,
                              const float* __restrict__ wts,
                              const float* __restrict__ b2,
                              float* __restrict__ out) {
  const int n = blockIdx.x;
  const int t = threadIdx.x;            // 256
  const int c = t * 8;                  // 8 cols per thread

  int slots[KSEL];
#pragma unroll
  for (int k = 0; k < KSEL; ++k) slots[k] = slot_map[n * KSEL + k];
  float w8[NEXP];
#pragma unroll
  for (int e = 0; e < NEXP; ++e) w8[e] = wts[n * NEXP + e];

  float s[8];
#pragma unroll
  for (int j = 0; j < 8; ++j) s[j] = 0.f;
#pragma unroll
  for (int e = 0; e < NEXP; ++e) {
    const float4 b0 = *(const float4*)(b2 + (size_t)e * ODIM + c);
    const float4 b1v = *(const float4*)(b2 + (size_t)e * ODIM + c + 4);
    s[0] += w8[e] * b0.x; s[1] += w8[e] * b0.y; s[2] += w8[e] * b0.z; s[3] += w8[e] * b0.w;
    s[4] += w8[e] * b1v.x; s[5] += w8[e] * b1v.y; s[6] += w8[e] * b1v.z; s[7] += w8[e] * b1v.w;
  }
#pragma unroll
  for (int k = 0; k < KSEL; ++k) {
    const ushort8 v = *(const ushort8*)(obuf + (size_t)slots[k] * ODIM + c);
#pragma unroll
    for (int j = 0; j < 8; ++j) s[j] += bf2f(v[j]);
  }
  float4 o0 = make_float4(s[0], s[1], s[2], s[3]);
  float4 o1 = make_float4(s[4], s[5], s[6], s[7]);
  *(float4*)(out + (size_t)n * ODIM + c) = o0;
  *(float4*)(out + (size_t)n * ODIM + c + 4) = o1;
}

// ---------------- launch ----------------

extern "C" void kernel_launch(void* const* d_in, const int* in_sizes, int n_in,
                              void* d_out, int out_size, void* d_ws, size_t ws_size,
                              hipStream_t stream) {
  const float* x    = (const float*)d_in[0];
  const float* Wg   = (const float*)d_in[1];
  const float* bg   = (const float*)d_in[2];
  const float* Wa   = (const float*)d_in[3];
  const float* ba   = (const float*)d_in[4];
  const float* Wb   = (const float*)d_in[5];
  const float* bb   = (const float*)d_in[6];
  const float* sigs = (const float*)d_in[7];
  const float* W1   = (const float*)d_in[8];
  const float* b1   = (const float*)d_in[9];
  const float* W2   = (const float*)d_in[10];
  const float* b2   = (const float*)d_in[11];
  float* out = (float*)d_out;

  char* ws = (char*)d_ws;
  float*    wts     = (float*)(ws + 0);           //   131072 B
  int*      selmask = (int*)(ws + 131072);        //    16384 B
  int*      cnt     = (int*)(ws + 147456);        //       32 B
  int*      base    = (int*)(ws + 147584);        //       32 B
  int*      slot_map= (int*)(ws + 151552);        //    81920 B
  float*    wrow    = (float*)(ws + 233472);      //    81920 B
  int*      list    = (int*)(ws + 315392);        //   131072 B -> 446464
  uint16_t* xbf     = (uint16_t*)(ws + 446464);   //  16777216 B -> 17223680
  uint16_t* W1T     = (uint16_t*)(ws + 17223680); // 134217728 B -> 151441408
  uint16_t* W2T     = (uint16_t*)(ws + 151441408);// 134217728 B -> 285659136
  uint16_t* hbuf    = (uint16_t*)(ws + 285659136);// 167772160 B -> 453431296
  uint16_t* obuf    = (uint16_t*)(ws + 453431296);//  83886080 B -> 537317376 (512.4 MB)

  cast_x_kernel<<<(TOK * DIM / 4) / 256, 256, 0, stream>>>(x, xbf, TOK * DIM / 4);
  // W1 [E][D][H] -> W1T [E][H][D]
  transpose_cast_kernel<<<dim3(HID / 32, DIM / 32, NEXP), dim3(32, 8), 0, stream>>>(
      W1, W1T, DIM, HID, (long)DIM * HID, (long)DIM * HID);
  // W2 [E][H][O] -> W2T [E][O][H]  (per-expert contiguous, 8KB B-row stride)
  transpose_cast_kernel<<<dim3(ODIM / 32, HID / 32, NEXP), dim3(32, 8), 0, stream>>>(
      W2, W2T, HID, ODIM, (long)HID * ODIM, (long)ODIM * HID);
  routing_kernel<<<TOK, 64, 0, stream>>>(x, Wg, bg, Wa, ba, Wb, bb, sigs, wts, selmask);
  listbuild_kernel<<<NEXP, 256, 0, stream>>>(selmask, wts, cnt, base, list, slot_map, wrow);

  gemm1_kernel<<<NEXP * 32 * 32, 256, 0, stream>>>(
      xbf, W1T, cnt, base, list, wrow, b1, hbuf);
  gemm2_kernel<<<NEXP * 32 * 16, 256, 0, stream>>>(
      hbuf, W2T, cnt, base, obuf);
  reduce_kernel<<<TOK, 256, 0, stream>>>(obuf, slot_map, wts, b2, out);
}

// Round 5
// 1529.360 us; speedup vs baseline: 1.4211x; 1.4211x over previous
//
#include <hip/hip_runtime.h>
#include <hip/hip_bf16.h>
#include <stdint.h>

#define TOK  4096
#define DIM  2048
#define HID  4096
#define ODIM 2048
#define NEXP 8
#define KSEL 5

typedef __bf16 bf16x8 __attribute__((ext_vector_type(8)));
typedef float  f32x4  __attribute__((ext_vector_type(4)));
typedef unsigned short ushort8 __attribute__((ext_vector_type(8)));

__device__ __forceinline__ uint16_t f2bf(float f) {
  uint32_t u = __float_as_uint(f);
  u += 0x7FFFu + ((u >> 16) & 1u);   // round-to-nearest-even
  return (uint16_t)(u >> 16);
}
__device__ __forceinline__ float bf2f(uint16_t h) {
  uint32_t u = ((uint32_t)h) << 16;
  return __uint_as_float(u);
}

#define GLD16(g, l) __builtin_amdgcn_global_load_lds(                      \
    (const __attribute__((address_space(1))) void*)(g),                    \
    (__attribute__((address_space(3))) void*)(l), 16, 0, 0)

// ---------------- convert kernels ----------------

__global__ void cast_x_kernel(const float* __restrict__ in,
                              uint16_t* __restrict__ out, int n4) {
  int i = blockIdx.x * blockDim.x + threadIdx.x;
  if (i >= n4) return;
  float4 v = ((const float4*)in)[i];
  ushort4 o;
  o.x = f2bf(v.x); o.y = f2bf(v.y); o.z = f2bf(v.z); o.w = f2bf(v.w);
  ((ushort4*)out)[i] = o;
}

// out[c*R + r] = bf16(in[r*C + c]), batched over blockIdx.z
__global__ void transpose_cast_kernel(const float* __restrict__ in,
                                      uint16_t* __restrict__ out,
                                      int R, int C, long inBatch, long outBatch) {
  __shared__ float tile[32][33];
  const float* src = in + (size_t)blockIdx.z * inBatch;
  uint16_t*    dst = out + (size_t)blockIdx.z * outBatch;
  int c0 = blockIdx.x * 32, r0 = blockIdx.y * 32;
  int tx = threadIdx.x, ty = threadIdx.y;   // (32, 8)
#pragma unroll
  for (int i = 0; i < 4; ++i)
    tile[ty + i * 8][tx] = src[(size_t)(r0 + ty + i * 8) * C + c0 + tx];
  __syncthreads();
#pragma unroll
  for (int i = 0; i < 4; ++i)
    dst[(size_t)(c0 + ty + i * 8) * R + r0 + tx] = f2bf(tile[tx][ty + i * 8]);
}

// ---------------- routing: weights + selection bitmask (pure, no atomics) ----------------

__global__ void routing_kernel(const float* __restrict__ x,
                               const float* __restrict__ Wg, const float* __restrict__ bg,
                               const float* __restrict__ Wa, const float* __restrict__ ba,
                               const float* __restrict__ Wb, const float* __restrict__ bb,
                               const float* __restrict__ sigs,
                               float* __restrict__ wts, int* __restrict__ selmask_g) {
  const int n    = blockIdx.x;
  const int lane = threadIdx.x;   // 64
  const float* xr = x + (size_t)n * DIM;

  float ga[NEXP]; float aa[32];
#pragma unroll
  for (int e = 0; e < NEXP; ++e) ga[e] = 0.f;
#pragma unroll
  for (int j = 0; j < 32; ++j) aa[j] = 0.f;

  for (int it = 0; it < DIM / 64; ++it) {
    int d = it * 64 + lane;
    float xv = xr[d];
    const float* wgr = Wg + (size_t)d * NEXP;
#pragma unroll
    for (int e = 0; e < NEXP; ++e) ga[e] += xv * wgr[e];
    const float* war = Wa + (size_t)d * 32;
#pragma unroll
    for (int j = 0; j < 32; ++j) aa[j] += xv * war[j];
  }
#pragma unroll
  for (int s = 1; s < 64; s <<= 1) {
#pragma unroll
    for (int e = 0; e < NEXP; ++e) ga[e] += __shfl_xor(ga[e], s);
#pragma unroll
    for (int j = 0; j < 32; ++j) aa[j] += __shfl_xor(aa[j], s);
  }

  float ph[16];
#pragma unroll
  for (int i = 0; i < 16; ++i) ph[i] = bb[i];
#pragma unroll
  for (int j = 0; j < 32; ++j) {
    float a = aa[j] + ba[j];
    a = a > 0.f ? a : 0.f;
#pragma unroll
    for (int i = 0; i < 16; ++i) ph[i] += a * Wb[j * 16 + i];
  }
  float nrm = 0.f;
#pragma unroll
  for (int i = 0; i < 16; ++i) nrm += ph[i] * ph[i];
  nrm = fmaxf(sqrtf(nrm), 1e-12f);

  const float invT = 0.36787944117144233f;  // 1/e
  float lg[NEXP], mx = -1e30f;
#pragma unroll
  for (int e = 0; e < NEXP; ++e) { lg[e] = (ga[e] + bg[e]) * invT; mx = fmaxf(mx, lg[e]); }
  float psum = 0.f, pr[NEXP];
#pragma unroll
  for (int e = 0; e < NEXP; ++e) { pr[e] = expf(lg[e] - mx); psum += pr[e]; }

  float eff[NEXP];
#pragma unroll
  for (int e = 0; e < NEXP; ++e) {
    const float* sg = sigs + e * 16;
    float dot = 0.f, sn = 0.f;
#pragma unroll
    for (int i = 0; i < 16; ++i) { dot += ph[i] * sg[i]; sn += sg[i] * sg[i]; }
    sn = fmaxf(sqrtf(sn), 1e-12f);
    float match = (dot / (nrm * sn) + 1.f) * 0.5f;
    eff[e] = (pr[e] / psum) * match;
  }

  int selmask = 0;
#pragma unroll
  for (int t = 0; t < KSEL; ++t) {
    int bi = 0; float bv = -1e30f;
#pragma unroll
    for (int e = 0; e < NEXP; ++e) {
      bool ok = !((selmask >> e) & 1);
      if (ok && eff[e] > bv) { bv = eff[e]; bi = e; }
    }
    selmask |= (1 << bi);
  }
  float wsum = 0.f, wv[NEXP];
#pragma unroll
  for (int e = 0; e < NEXP; ++e) {
    wv[e] = ((selmask >> e) & 1) ? eff[e] : 0.f;
    wsum += wv[e];
  }
  float inv = 1.f / (wsum + 1e-8f);
  if (lane == 0) {
#pragma unroll
    for (int e = 0; e < NEXP; ++e) wts[n * NEXP + e] = wv[e] * inv;
    selmask_g[n] = selmask;
  }
}

// ---------------- deterministic sorted list build (1 block per expert) ----------------

__global__ void listbuild_kernel(const int* __restrict__ selmask_g,
                                 const float* __restrict__ wts,
                                 int* __restrict__ cnt, int* __restrict__ base,
                                 int* __restrict__ list, int* __restrict__ slot_map,
                                 float* __restrict__ wrow) {
  const int e = blockIdx.x;      // 0..7
  const int t = threadIdx.x;     // 0..255, each owns 16 consecutive tokens
  __shared__ int cntT[256][NEXP];
  __shared__ int totAll[NEXP];
  __shared__ int sc[256];

  int msk[16];
  int c8[NEXP];
#pragma unroll
  for (int f = 0; f < NEXP; ++f) c8[f] = 0;
#pragma unroll
  for (int i = 0; i < 16; ++i) {
    msk[i] = selmask_g[t * 16 + i];
#pragma unroll
    for (int f = 0; f < NEXP; ++f) c8[f] += (msk[i] >> f) & 1;
  }
#pragma unroll
  for (int f = 0; f < NEXP; ++f) cntT[t][f] = c8[f];
  __syncthreads();

  if (t < NEXP) {
    int s = 0;
    for (int j = 0; j < 256; ++j) s += cntT[j][t];
    totAll[t] = s;
  }
  __syncthreads();

  if (e == 0 && t == 0) {
    int r = 0;
    for (int f = 0; f < NEXP; ++f) { cnt[f] = totAll[f]; base[f] = r; r += totAll[f]; }
  }
  int gbase = 0;
  for (int f = 0; f < e; ++f) gbase += totAll[f];

  // exclusive prefix over threads for expert e
  sc[t] = c8[e];
  __syncthreads();
  for (int off = 1; off < 256; off <<= 1) {
    int v = (t >= off) ? sc[t - off] : 0;
    __syncthreads();
    sc[t] += v;
    __syncthreads();
  }
  int p = sc[t] - c8[e];

#pragma unroll
  for (int i = 0; i < 16; ++i) {
    const int n = t * 16 + i;
    const int m = msk[i];
    if ((m >> e) & 1) {
      list[e * TOK + p] = n;
      const int rank = __popc(m & ((1 << e) - 1));
      slot_map[n * KSEL + rank] = gbase + p;
      wrow[gbase + p] = wts[n * NEXP + e];
      ++p;
    }
  }
}

// ---------------- pipelined GEMM (BM=BN=256, BK=32, 8 waves, 4 LDS slots) ----------------
// A [rows, Kdim] bf16 (MODE1: gathered via list; MODE2: compact), Bt [E][Ncols][Kdim] bf16.
// K-major LDS granule layout per slot: A: elem (g*256 + r)*8 holds A[r][k0+g*8..+8]; B likewise.
// Schedule: compute tile T from slot T&3; during T issue stages for T+3 into slot (T+3)&3
// = (T-1)&3 (freed at end of T-1 -> GLD writes can never race live reads).
// Waits: vmcnt(8) at tile top (T+1,T+2 remain in flight), vmcnt(4)/vmcnt(0) for the tail.

template <int MODE>
__launch_bounds__(512, 2)
__global__ void gemm_pipe_kernel(const uint16_t* __restrict__ A,
                                 const uint16_t* __restrict__ Bt,
                                 const int* __restrict__ cnt,
                                 const int* __restrict__ base,
                                 const int* __restrict__ list,
                                 const float* __restrict__ wrow,
                                 const float* __restrict__ bias,
                                 uint16_t* __restrict__ outb,
                                 int Kdim, int NTk, int Ncols) {
  __shared__ __attribute__((aligned(16))) uint16_t lds[4 * 16384];  // 128 KiB, 4 slots

  const int e  = blockIdx.z;
  const int ce = cnt[e];
  const int tileM = blockIdx.y * 256;
  if (tileM >= ce) return;
  const int be    = base[e];
  const int tileN = blockIdx.x * 256;
  const int tid = threadIdx.x, lane = tid & 63, wid = tid >> 6;
  const int wr = wid >> 2, wc = wid & 3;         // wave tile: 128 rows x 64 cols
  const int sr = (wid & 3) * 64 + lane;          // staging row 0..255
  const int sg = wid >> 2;                       // staging granule sub (0..1)

  // staging source row pointers
  int pA = tileM + sr; pA = pA < ce ? pA : ce - 1;
  const uint16_t* aRow;
  if (MODE == 1) aRow = A + (size_t)list[e * TOK + pA] * Kdim;
  else           aRow = A + (size_t)(be + pA) * Kdim;
  const uint16_t* bRow = Bt + ((size_t)e * Ncols + tileN + sr) * Kdim;

  // per-wave LDS staging byte base (linear dest; lane*16B added by HW)
  char* lbase = (char*)lds + wid * 1024;

#define STAGE_A(slotIdx, kOff)                                   \
  { char* lb = lbase + (slotIdx) * 32768;                        \
    GLD16(aRow + (kOff) + sg * 8,       lb);                     \
    GLD16(aRow + (kOff) + (2 + sg) * 8, lb + 8192); }
#define STAGE_B(slotIdx, kOff)                                   \
  { char* lb = lbase + (slotIdx) * 32768 + 16384;                \
    GLD16(bRow + (kOff) + sg * 8,       lb);                     \
    GLD16(bRow + (kOff) + (2 + sg) * 8, lb + 8192); }

  // fragment read offsets (elems), conflict-free: quarter-wave reads 256B contiguous
  const int afrag = ((lane >> 4) << 8) + wr * 128 + (lane & 15);
  const int bfrag = ((lane >> 4) << 8) + wc * 64 + (lane & 15);

  f32x4 acc[8][4];
#pragma unroll
  for (int m = 0; m < 8; ++m)
#pragma unroll
    for (int n = 0; n < 4; ++n) acc[m][n] = (f32x4){0.f, 0.f, 0.f, 0.f};

  // prologue: stage T0, T1, T2 (12 GLDs, FIFO oldest-first)
  STAGE_A(0, 0);  STAGE_B(0, 0);
  STAGE_A(1, 32); STAGE_B(1, 32);
  STAGE_A(2, 64); STAGE_B(2, 64);

  for (int T = 0; T < NTk; ++T) {
    // ---- tile top: wait for T's stages (issued 3 tiles ago), then sync ----
    if (T + 2 < NTk)      asm volatile("s_waitcnt vmcnt(8)" ::: "memory");
    else if (T + 1 < NTk) asm volatile("s_waitcnt vmcnt(4)" ::: "memory");
    else                  asm volatile("s_waitcnt vmcnt(0)" ::: "memory");
    __builtin_amdgcn_sched_barrier(0);
    __builtin_amdgcn_s_barrier();

    const uint16_t* As = lds + (T & 3) * 16384;
    const uint16_t* Bs = As + 8192;
    const int kNext = (T + 3) * 32;
    const bool doStage = (T + 3) < NTk;

    // ---- phase 0: read A frags (8) + B frags n0,n1; stage A of T+3; MFMA n0,n1 ----
    bf16x8 av[8];
#pragma unroll
    for (int m = 0; m < 8; ++m)
      av[m] = *(const bf16x8*)(As + (size_t)(afrag + m * 16) * 8);
    bf16x8 bv0 = *(const bf16x8*)(Bs + (size_t)(bfrag + 0 * 16) * 8);
    bf16x8 bv1 = *(const bf16x8*)(Bs + (size_t)(bfrag + 1 * 16) * 8);
    if (doStage) STAGE_A((T + 3) & 3, kNext);
    __builtin_amdgcn_s_barrier();
    asm volatile("s_waitcnt lgkmcnt(0)" ::: "memory");
    __builtin_amdgcn_sched_barrier(0);
    __builtin_amdgcn_s_setprio(1);
#pragma unroll
    for (int m = 0; m < 8; ++m)
      acc[m][0] = __builtin_amdgcn_mfma_f32_16x16x32_bf16(av[m], bv0, acc[m][0], 0, 0, 0);
#pragma unroll
    for (int m = 0; m < 8; ++m)
      acc[m][1] = __builtin_amdgcn_mfma_f32_16x16x32_bf16(av[m], bv1, acc[m][1], 0, 0, 0);
    __builtin_amdgcn_s_setprio(0);

    // ---- phase 1: read B frags n2,n3; stage B of T+3; MFMA n2,n3 ----
    bf16x8 bv2 = *(const bf16x8*)(Bs + (size_t)(bfrag + 2 * 16) * 8);
    bf16x8 bv3 = *(const bf16x8*)(Bs + (size_t)(bfrag + 3 * 16) * 8);
    if (doStage) STAGE_B((T + 3) & 3, kNext);
    __builtin_amdgcn_s_barrier();
    asm volatile("s_waitcnt lgkmcnt(0)" ::: "memory");
    __builtin_amdgcn_sched_barrier(0);
    __builtin_amdgcn_s_setprio(1);
#pragma unroll
    for (int m = 0; m < 8; ++m)
      acc[m][2] = __builtin_amdgcn_mfma_f32_16x16x32_bf16(av[m], bv2, acc[m][2], 0, 0, 0);
#pragma unroll
    for (int m = 0; m < 8; ++m)
      acc[m][3] = __builtin_amdgcn_mfma_f32_16x16x32_bf16(av[m], bv3, acc[m][3], 0, 0, 0);
    __builtin_amdgcn_s_setprio(0);
  }
#undef STAGE_A
#undef STAGE_B

  // ---- epilogue ----
  if (MODE == 1) {
    const float* b1e = bias + (size_t)e * Ncols;
#pragma unroll
    for (int m = 0; m < 8; ++m)
#pragma unroll
      for (int r = 0; r < 4; ++r) {
        const int p = tileM + wr * 128 + m * 16 + ((lane >> 4) << 2) + r;
        if (p < ce) {
          const float w = wrow[be + p];
          uint16_t* orow = outb + (size_t)(be + p) * Ncols;
#pragma unroll
          for (int n = 0; n < 4; ++n) {
            const int col = tileN + wc * 64 + n * 16 + (lane & 15);
            float v = acc[m][n][r] + b1e[col];
            v = v > 0.f ? v : 0.f;
            orow[col] = f2bf(v * w);
          }
        }
      }
  } else {
#pragma unroll
    for (int m = 0; m < 8; ++m)
#pragma unroll
      for (int r = 0; r < 4; ++r) {
        const int p = tileM + wr * 128 + m * 16 + ((lane >> 4) << 2) + r;
        if (p < ce) {
          uint16_t* orow = outb + (size_t)(be + p) * Ncols;
#pragma unroll
          for (int n = 0; n < 4; ++n) {
            const int col = tileN + wc * 64 + n * 16 + (lane & 15);
            orow[col] = f2bf(acc[m][n][r]);
          }
        }
      }
  }
}

// ---------------- reduce: out[n,:] = sum_e w*b2[e,:] + sum_{k<5} obuf[slot_k,:] ----------------

__global__ void reduce_kernel(const uint16_t* __restrict__ obuf,
                              const int* __restrict__ slot_map,
                              const float* __restrict__ wts,
                              const float* __restrict__ b2,
                              float* __restrict__ out) {
  const int n = blockIdx.x;
  const int t = threadIdx.x;            // 256
  const int c = t * 8;                  // 8 cols per thread

  int slots[KSEL];
#pragma unroll
  for (int k = 0; k < KSEL; ++k) slots[k] = slot_map[n * KSEL + k];
  float w8[NEXP];
#pragma unroll
  for (int e = 0; e < NEXP; ++e) w8[e] = wts[n * NEXP + e];

  float s[8];
#pragma unroll
  for (int j = 0; j < 8; ++j) s[j] = 0.f;
#pragma unroll
  for (int e = 0; e < NEXP; ++e) {
    const float4 b0 = *(const float4*)(b2 + (size_t)e * ODIM + c);
    const float4 b1v = *(const float4*)(b2 + (size_t)e * ODIM + c + 4);
    s[0] += w8[e] * b0.x; s[1] += w8[e] * b0.y; s[2] += w8[e] * b0.z; s[3] += w8[e] * b0.w;
    s[4] += w8[e] * b1v.x; s[5] += w8[e] * b1v.y; s[6] += w8[e] * b1v.z; s[7] += w8[e] * b1v.w;
  }
#pragma unroll
  for (int k = 0; k < KSEL; ++k) {
    const ushort8 v = *(const ushort8*)(obuf + (size_t)slots[k] * ODIM + c);
#pragma unroll
    for (int j = 0; j < 8; ++j) s[j] += bf2f(v[j]);
  }
  float4 o0 = make_float4(s[0], s[1], s[2], s[3]);
  float4 o1 = make_float4(s[4], s[5], s[6], s[7]);
  *(float4*)(out + (size_t)n * ODIM + c) = o0;
  *(float4*)(out + (size_t)n * ODIM + c + 4) = o1;
}

// ---------------- launch ----------------

extern "C" void kernel_launch(void* const* d_in, const int* in_sizes, int n_in,
                              void* d_out, int out_size, void* d_ws, size_t ws_size,
                              hipStream_t stream) {
  const float* x    = (const float*)d_in[0];
  const float* Wg   = (const float*)d_in[1];
  const float* bg   = (const float*)d_in[2];
  const float* Wa   = (const float*)d_in[3];
  const float* ba   = (const float*)d_in[4];
  const float* Wb   = (const float*)d_in[5];
  const float* bb   = (const float*)d_in[6];
  const float* sigs = (const float*)d_in[7];
  const float* W1   = (const float*)d_in[8];
  const float* b1   = (const float*)d_in[9];
  const float* W2   = (const float*)d_in[10];
  const float* b2   = (const float*)d_in[11];
  float* out = (float*)d_out;

  char* ws = (char*)d_ws;
  float*    wts     = (float*)(ws + 0);           //   131072 B
  int*      selmask = (int*)(ws + 131072);        //    16384 B
  int*      cnt     = (int*)(ws + 147456);        //       32 B
  int*      base    = (int*)(ws + 147584);        //       32 B
  int*      slot_map= (int*)(ws + 151552);        //    81920 B
  float*    wrow    = (float*)(ws + 233472);      //    81920 B
  int*      list    = (int*)(ws + 315392);        //   131072 B -> 446464
  uint16_t* xbf     = (uint16_t*)(ws + 446464);   //  16777216 B -> 17223680
  uint16_t* W1T     = (uint16_t*)(ws + 17223680); // 134217728 B -> 151441408
  uint16_t* W2T     = (uint16_t*)(ws + 151441408);// 134217728 B -> 285659136
  uint16_t* hbuf    = (uint16_t*)(ws + 285659136);// 167772160 B -> 453431296
  uint16_t* obuf    = (uint16_t*)(ws + 453431296);//  83886080 B -> 537317376 (512.4 MB)

  cast_x_kernel<<<(TOK * DIM / 4) / 256, 256, 0, stream>>>(x, xbf, TOK * DIM / 4);
  // W1 [E][D][H] -> W1T [E][H][D]
  transpose_cast_kernel<<<dim3(HID / 32, DIM / 32, NEXP), dim3(32, 8), 0, stream>>>(
      W1, W1T, DIM, HID, (long)DIM * HID, (long)DIM * HID);
  // W2 [E][H][O] -> W2T [E][O][H]  (per-expert contiguous, 8KB B-row stride)
  transpose_cast_kernel<<<dim3(ODIM / 32, HID / 32, NEXP), dim3(32, 8), 0, stream>>>(
      W2, W2T, HID, ODIM, (long)HID * ODIM, (long)ODIM * HID);
  routing_kernel<<<TOK, 64, 0, stream>>>(x, Wg, bg, Wa, ba, Wb, bb, sigs, wts, selmask);
  listbuild_kernel<<<NEXP, 256, 0, stream>>>(selmask, wts, cnt, base, list, slot_map, wrow);

  // gemm1: hbuf[be+p, col] = bf16( wrow * relu( x[list[p],:] @ W1[e][:,col] + b1[e,col] ) )
  gemm_pipe_kernel<1><<<dim3(HID / 256, 16, NEXP), 512, 0, stream>>>(
      xbf, W1T, cnt, base, list, wrow, b1, hbuf, DIM, DIM / 32, HID);
  // gemm2: obuf[be+p, col] = bf16( hbuf[be+p, :] @ W2[e][:, col] )
  gemm_pipe_kernel<2><<<dim3(ODIM / 256, 16, NEXP), 512, 0, stream>>>(
      hbuf, W2T, cnt, base, nullptr, nullptr, nullptr, obuf, HID, HID / 32, ODIM);
  reduce_kernel<<<TOK, 256, 0, stream>>>(obuf, slot_map, wts, b2, out);
}